// Round 1
// baseline (632.103 us; speedup 1.0000x reference)
//
#include <hip/hip_runtime.h>

typedef unsigned short u16;
typedef __bf16 bf16x8 __attribute__((ext_vector_type(8)));
typedef float f32x4 __attribute__((ext_vector_type(4)));
typedef u16 u16x4 __attribute__((ext_vector_type(4)));

#define LOG2E_OVER_8 0.18033688011112043f

__device__ __forceinline__ u16 f2bf(float f) {
  union { float f; unsigned int u; } x{f};
  unsigned int r = (x.u + 0x7fffu + ((x.u >> 16) & 1u)) >> 16;
  return (u16)r;
}

__device__ __forceinline__ void gld16(const void* g, void* l) {
  __builtin_amdgcn_global_load_lds((const __attribute__((address_space(1))) unsigned int*)g,
                                   (__attribute__((address_space(3))) unsigned int*)l,
                                   16, 0, 0);
}

// ---------------- weight prep: W^T -> bf16 (Wq scaled, Wc = 8*Wg + Wbeta) ----
__global__ void prep_w(const float* __restrict__ Wq, const float* __restrict__ Wk,
                       const float* __restrict__ Wv, const float* __restrict__ Wg,
                       const float* __restrict__ Wb, const float* __restrict__ Wo,
                       u16* __restrict__ Wqt, u16* __restrict__ Wkt, u16* __restrict__ Wvt,
                       u16* __restrict__ Wct, u16* __restrict__ Wot)
{
  __shared__ float tile[32][33];
  const int m = blockIdx.z;
  const int nb = blockIdx.x * 32, kb = blockIdx.y * 32;
  const int tx = threadIdx.x, ty = threadIdx.y;
  const float* src = (m == 0) ? Wq : (m == 1) ? Wk : (m == 2) ? Wv : (m == 3) ? Wg : Wo;
  u16* dst = (m == 0) ? Wqt : (m == 1) ? Wkt : (m == 2) ? Wvt : (m == 3) ? Wct : Wot;
#pragma unroll
  for (int i = 0; i < 4; ++i) {
    const int k = kb + ty + i * 8;
    float v = src[k * 1024 + nb + tx];
    if (m == 3) v = 8.0f * v + Wb[k * 1024 + nb + tx];
    if (m == 0) v *= LOG2E_OVER_8;
    tile[ty + i * 8][tx] = v;
  }
  __syncthreads();
#pragma unroll
  for (int i = 0; i < 4; ++i) {
    const int r = ty + i * 8;
    dst[(nb + r) * 1024 + kb + tx] = f2bf(tile[tx][r]);
  }
}

__global__ void prep_b(const float* __restrict__ bq, const float* __restrict__ bg,
                       const float* __restrict__ bb,
                       float* __restrict__ bqs, float* __restrict__ bcs)
{
  const int i = blockIdx.x * 256 + threadIdx.x;
  if (i < 1024) {
    bqs[i] = bq[i] * LOG2E_OVER_8;
    bcs[i] = 8.0f * bg[i] + bb[i];
  }
}

// ---------------- f32 -> bf16 convert ----------------------------------------
__global__ void cvt_bf16(const float* __restrict__ in, u16* __restrict__ out, int n)
{
  int i = (blockIdx.x * blockDim.x + threadIdx.x) * 4;
  const int stride = gridDim.x * blockDim.x * 4;
  for (; i < n; i += stride) {
    const float4 v = *reinterpret_cast<const float4*>(in + i);
    u16x4 o;
    o.x = f2bf(v.x); o.y = f2bf(v.y); o.z = f2bf(v.z); o.w = f2bf(v.w);
    *reinterpret_cast<u16x4*>(out + i) = o;
  }
}

// ---------------- GEMM: C[8192x1024] = A[8192x1024] @ Bt^T + bias ------------
// Bt is [N=1024][K=1024] (pre-transposed weight). m97 structure: 128x128 tile,
// BK=32, 4 waves 2x2, global_load_lds width 16, 2-barrier K-loop.
// EPI: 0 = bf16 out; 1 = fp32 + bf16 out; 2 = bf16 out transposed per head
//      Vt[b][h][d][s]; 3 = fp32 out only.
template<int EPI>
__global__ __launch_bounds__(256, 2)
void gemm_k(const u16* __restrict__ A, const u16* __restrict__ Bt,
            const float* __restrict__ bias,
            u16* __restrict__ outb, float* __restrict__ outf)
{
  __shared__ u16 lA[128 * 32];
  __shared__ u16 lB[128 * 32];
  int bid = (int)blockIdx.x;
  bid = (bid & 7) * 64 + (bid >> 3);       // XCD-contiguous row bands (512 % 8 == 0)
  const int row0 = (bid >> 3) * 128;
  const int col0 = (bid & 7) * 128;
  const int t = threadIdx.x;
  const int w = t >> 6, lane = t & 63;
  const int l15 = lane & 15, l4 = lane >> 4;
  const int wr = w >> 1, wc = w & 1;

  const int c0 = t, c1 = 256 + t;
  const u16* gA0 = A + (row0 + (c0 >> 2)) * 1024 + (c0 & 3) * 8;
  const u16* gA1 = A + (row0 + (c1 >> 2)) * 1024 + (c1 & 3) * 8;
  const u16* gB0 = Bt + (col0 + (c0 >> 2)) * 1024 + (c0 & 3) * 8;
  const u16* gB1 = Bt + (col0 + (c1 >> 2)) * 1024 + (c1 & 3) * 8;
  u16* lA0 = lA + (w * 64) * 8;
  u16* lA1 = lA + (256 + w * 64) * 8;
  u16* lB0 = lB + (w * 64) * 8;
  u16* lB1 = lB + (256 + w * 64) * 8;

  f32x4 acc[4][4] = {};

  for (int kt = 0; kt < 1024; kt += 32) {
    gld16(gA0 + kt, lA0);
    gld16(gA1 + kt, lA1);
    gld16(gB0 + kt, lB0);
    gld16(gB1 + kt, lB1);
    __syncthreads();
    bf16x8 aF[4], bF[4];
#pragma unroll
    for (int m = 0; m < 4; ++m)
      aF[m] = *reinterpret_cast<const bf16x8*>(&lA[(wr * 64 + m * 16 + l15) * 32 + l4 * 8]);
#pragma unroll
    for (int n = 0; n < 4; ++n)
      bF[n] = *reinterpret_cast<const bf16x8*>(&lB[(wc * 64 + n * 16 + l15) * 32 + l4 * 8]);
#pragma unroll
    for (int m = 0; m < 4; ++m)
#pragma unroll
      for (int n = 0; n < 4; ++n)
        acc[m][n] = __builtin_amdgcn_mfma_f32_16x16x32_bf16(aF[m], bF[n], acc[m][n], 0, 0, 0);
    __syncthreads();
  }

  float bv[4];
#pragma unroll
  for (int n = 0; n < 4; ++n) bv[n] = bias[col0 + wc * 64 + n * 16 + l15];
#pragma unroll
  for (int m = 0; m < 4; ++m) {
#pragma unroll
    for (int n = 0; n < 4; ++n) {
      const int c = col0 + wc * 64 + n * 16 + l15;
#pragma unroll
      for (int j = 0; j < 4; ++j) {
        const int r = row0 + wr * 64 + m * 16 + l4 * 4 + j;
        const float v = acc[m][n][j] + bv[n];
        if constexpr (EPI == 0) {
          outb[r * 1024 + c] = f2bf(v);
        } else if constexpr (EPI == 1) {
          outf[r * 1024 + c] = v;
          outb[r * 1024 + c] = f2bf(v);
        } else if constexpr (EPI == 2) {
          const int bi = r >> 10, s = r & 1023;
          const int h = c >> 6, d = c & 63;
          outb[((bi * 16 + h) * 64 + d) * 1024 + s] = f2bf(v);
        } else {
          outf[r * 1024 + c] = v;
        }
      }
    }
  }
}

// ---------------- flash attention: Q,K [8192x1024] per-head cols, Vt[b][h][64][1024]
// scores pre-scaled by log2(e)/8 (folded into Wq/bq), softmax via exp2.
__global__ __launch_bounds__(256, 2)
void attn_k(const u16* __restrict__ Q, const u16* __restrict__ K,
            const u16* __restrict__ Vt, u16* __restrict__ ctx)
{
  __shared__ u16 P[4][32 * 72];   // per-wave P tile [32 q][64 kv], stride 72 (pad)
  const int qt = blockIdx.x, h = blockIdx.y, b = blockIdx.z;
  const int t = threadIdx.x, w = t >> 6, lane = t & 63;
  const int l15 = lane & 15, l4 = lane >> 4;
  const int q0 = qt * 128 + w * 32;
  const u16* Qp = Q + (size_t)b * 1024 * 1024 + h * 64;
  const u16* Kp = K + (size_t)b * 1024 * 1024 + h * 64;
  const u16* Vp = Vt + (size_t)(b * 16 + h) * 64 * 1024;
  u16* Pw = P[w];

  bf16x8 aQ[2][2];
#pragma unroll
  for (int qf = 0; qf < 2; ++qf)
#pragma unroll
    for (int ks = 0; ks < 2; ++ks)
      aQ[qf][ks] = *reinterpret_cast<const bf16x8*>(
          &Qp[(q0 + qf * 16 + l15) * 1024 + ks * 32 + l4 * 8]);

  f32x4 acc[2][4] = {};
  float mrow[2][4], lrow[2][4];
#pragma unroll
  for (int qf = 0; qf < 2; ++qf)
#pragma unroll
    for (int j = 0; j < 4; ++j) { mrow[qf][j] = -1e30f; lrow[qf][j] = 0.f; }

  for (int kv0 = 0; kv0 < 1024; kv0 += 64) {
    // S = Q K^T (pre-scaled); S-frag: col=kv(l15), row=q(l4*4+j)
    f32x4 s[2][4] = {};
#pragma unroll
    for (int ks = 0; ks < 2; ++ks) {
#pragma unroll
      for (int kf = 0; kf < 4; ++kf) {
        const bf16x8 bK = *reinterpret_cast<const bf16x8*>(
            &Kp[(kv0 + kf * 16 + l15) * 1024 + ks * 32 + l4 * 8]);
#pragma unroll
        for (int qf = 0; qf < 2; ++qf)
          s[qf][kf] = __builtin_amdgcn_mfma_f32_16x16x32_bf16(aQ[qf][ks], bK, s[qf][kf], 0, 0, 0);
      }
    }
    // online softmax (row stats reduce over low-4 lane bits)
#pragma unroll
    for (int qf = 0; qf < 2; ++qf) {
      float psc[4];
#pragma unroll
      for (int j = 0; j < 4; ++j) {
        float tm = fmaxf(fmaxf(s[qf][0][j], s[qf][1][j]), fmaxf(s[qf][2][j], s[qf][3][j]));
        tm = fmaxf(tm, __shfl_xor(tm, 1));
        tm = fmaxf(tm, __shfl_xor(tm, 2));
        tm = fmaxf(tm, __shfl_xor(tm, 4));
        tm = fmaxf(tm, __shfl_xor(tm, 8));
        const float nm = fmaxf(mrow[qf][j], tm);
        psc[j] = __builtin_amdgcn_exp2f(mrow[qf][j] - nm);
        mrow[qf][j] = nm;
        float rs = 0.f;
#pragma unroll
        for (int kf = 0; kf < 4; ++kf) {
          const float p = __builtin_amdgcn_exp2f(s[qf][kf][j] - nm);
          s[qf][kf][j] = p;
          rs += p;
        }
        rs += __shfl_xor(rs, 1); rs += __shfl_xor(rs, 2);
        rs += __shfl_xor(rs, 4); rs += __shfl_xor(rs, 8);
        lrow[qf][j] = lrow[qf][j] * psc[j] + rs;
      }
#pragma unroll
      for (int df = 0; df < 4; ++df)
#pragma unroll
        for (int j = 0; j < 4; ++j) acc[qf][df][j] *= psc[j];
      // P -> LDS (bf16), layout [q][kv] so PV A-frag is contiguous b128
#pragma unroll
      for (int kf = 0; kf < 4; ++kf)
#pragma unroll
        for (int j = 0; j < 4; ++j)
          Pw[(qf * 16 + l4 * 4 + j) * 72 + kf * 16 + l15] = f2bf(s[qf][kf][j]);
    }
    // ctx += P @ V  (V read from transposed Vt: contiguous along kv)
#pragma unroll
    for (int kvs = 0; kvs < 2; ++kvs) {
      bf16x8 aP[2];
#pragma unroll
      for (int qf = 0; qf < 2; ++qf)
        aP[qf] = *reinterpret_cast<const bf16x8*>(&Pw[(qf * 16 + l15) * 72 + kvs * 32 + l4 * 8]);
#pragma unroll
      for (int df = 0; df < 4; ++df) {
        const bf16x8 bV = *reinterpret_cast<const bf16x8*>(
            &Vp[(df * 16 + l15) * 1024 + kv0 + kvs * 32 + l4 * 8]);
#pragma unroll
        for (int qf = 0; qf < 2; ++qf)
          acc[qf][df] = __builtin_amdgcn_mfma_f32_16x16x32_bf16(aP[qf], bV, acc[qf][df], 0, 0, 0);
      }
    }
  }

  u16* Cp = ctx + (size_t)b * 1024 * 1024 + h * 64;
#pragma unroll
  for (int qf = 0; qf < 2; ++qf)
#pragma unroll
    for (int j = 0; j < 4; ++j) {
      const float inv = 1.0f / lrow[qf][j];
      const int r = q0 + qf * 16 + l4 * 4 + j;
#pragma unroll
      for (int df = 0; df < 4; ++df)
        Cp[r * 1024 + df * 16 + l15] = f2bf(acc[qf][df][j] * inv);
    }
}

// ---------------- driver ------------------------------------------------------
extern "C" void kernel_launch(void* const* d_in, const int* in_sizes, int n_in,
                              void* d_out, int out_size, void* d_ws, size_t ws_size,
                              hipStream_t stream)
{
  (void)in_sizes; (void)n_in; (void)out_size; (void)ws_size;
  const float* X  = (const float*)d_in[0];
  const float* Y  = (const float*)d_in[1];
  const float* Wq = (const float*)d_in[2];
  const float* bq = (const float*)d_in[3];
  const float* Wk = (const float*)d_in[4];
  const float* bk = (const float*)d_in[5];
  const float* Wv = (const float*)d_in[6];
  const float* bv = (const float*)d_in[7];
  const float* Wg = (const float*)d_in[8];
  const float* bg = (const float*)d_in[9];
  const float* Wb = (const float*)d_in[10];
  const float* bb = (const float*)d_in[11];
  const float* Wo = (const float*)d_in[12];
  const float* bo = (const float*)d_in[13];
  float* out = (float*)d_out;
  char* ws = (char*)d_ws;
  const size_t MB = 1024ull * 1024ull;

  u16* Wqt = (u16*)(ws + 0 * MB);
  u16* Wkt = (u16*)(ws + 2 * MB);
  u16* Wvt = (u16*)(ws + 4 * MB);
  u16* Wct = (u16*)(ws + 6 * MB);
  u16* Wot = (u16*)(ws + 8 * MB);
  float* bqs = (float*)(ws + 10 * MB);
  float* bcs = (float*)(ws + 10 * MB + 8192);
  u16* Xb = (u16*)(ws + 12 * MB);
  u16* Yb = (u16*)(ws + 28 * MB);   // original Y bf16; later reused for Y_new bf16
  u16* Qb = (u16*)(ws + 44 * MB);   // Q; later reused for mid
  u16* Kb = (u16*)(ws + 60 * MB);
  u16* Vt = (u16*)(ws + 76 * MB);
  u16* Cx = (u16*)(ws + 92 * MB);
  const int NEL = 8 * 1024 * 1024;

  prep_w<<<dim3(32, 32, 5), dim3(32, 8), 0, stream>>>(Wq, Wk, Wv, Wg, Wb, Wo,
                                                      Wqt, Wkt, Wvt, Wct, Wot);
  prep_b<<<4, 256, 0, stream>>>(bq, bg, bb, bqs, bcs);
  cvt_bf16<<<2048, 256, 0, stream>>>(X, Xb, NEL);
  cvt_bf16<<<2048, 256, 0, stream>>>(Y, Yb, NEL);

  // pass 1: queries from X, kv from Y  -> Y_new
  gemm_k<0><<<512, 256, 0, stream>>>(Xb, Wqt, bqs, Qb, nullptr);
  gemm_k<0><<<512, 256, 0, stream>>>(Yb, Wkt, bk, Kb, nullptr);
  gemm_k<2><<<512, 256, 0, stream>>>(Yb, Wvt, bv, Vt, nullptr);
  attn_k<<<dim3(8, 16, 8), 256, 0, stream>>>(Qb, Kb, Vt, Cx);
  gemm_k<0><<<512, 256, 0, stream>>>(Cx, Wct, bcs, Qb, nullptr);          // mid
  gemm_k<1><<<512, 256, 0, stream>>>(Qb, Wot, bo, Yb, out + NEL);          // Y_new (f32 + bf16)

  // pass 2: queries from Y_new, kv from X -> X_new
  gemm_k<0><<<512, 256, 0, stream>>>(Yb, Wqt, bqs, Qb, nullptr);
  gemm_k<0><<<512, 256, 0, stream>>>(Xb, Wkt, bk, Kb, nullptr);
  gemm_k<2><<<512, 256, 0, stream>>>(Xb, Wvt, bv, Vt, nullptr);
  attn_k<<<dim3(8, 16, 8), 256, 0, stream>>>(Qb, Kb, Vt, Cx);
  gemm_k<0><<<512, 256, 0, stream>>>(Cx, Wct, bcs, Qb, nullptr);          // mid
  gemm_k<3><<<512, 256, 0, stream>>>(Qb, Wot, bo, nullptr, out);          // X_new (f32)
}